// Round 6
// baseline (89.300 us; speedup 1.0000x reference)
//
#include <hip/hip_runtime.h>
#include <hip/hip_bf16.h>

#define LPOS 8192
#define HDIM 128
#define M_TOT 4096          // B*Cin
#define GROW  132           // gp/g row stride (129 used)
#define GELEMS (M_TOT * GROW)
#define KSPLIT 32
#define BK 256              // k per block (2 halves of 128)
#define BM 128              // rows per block
#define CUNITS 1024         // 16-B units per 64-k chunk of h2T

typedef float  f32x4 __attribute__((ext_vector_type(4)));
typedef short  s16x8 __attribute__((ext_vector_type(8)));
typedef unsigned int u32x2 __attribute__((ext_vector_type(2)));
typedef unsigned int u32x4 __attribute__((ext_vector_type(4)));

__device__ __forceinline__ unsigned short bf16_rne(float f) {
    unsigned u = __builtin_bit_cast(unsigned, f);
    u += 0x7fffu + ((u >> 16) & 1u);
    return (unsigned short)(u >> 16);
}

__device__ __forceinline__ s16x8 cvt8(f32x4 a, f32x4 b) {
    s16x8 r;
    r[0] = (short)bf16_rne(a[0]); r[1] = (short)bf16_rne(a[1]);
    r[2] = (short)bf16_rne(a[2]); r[3] = (short)bf16_rne(a[3]);
    r[4] = (short)bf16_rne(b[0]); r[5] = (short)bf16_rne(b[1]);
    r[6] = (short)bf16_rne(b[2]); r[7] = (short)bf16_rne(b[3]);
    return r;
}

__device__ __forceinline__ float sum8(f32x4 a, f32x4 b) {
    return ((a[0] + a[1]) + (a[2] + a[3])) + ((b[0] + b[1]) + (b[2] + b[3]));
}

// ---------------- Kernel 1: SIREN -> h2T -------------------------------------
// h2T 16-B units: unit = chunk*1024 + k8*128 + h   (chunk = l/64, k8 = (l/8)%8)
__global__ __launch_bounds__(256) void k1_siren(
        const float* __restrict__ w1, const float* __restrict__ b1,
        const float* __restrict__ w2, const float* __restrict__ b2,
        unsigned short* __restrict__ h2T) {
    __shared__ float w2sT[HDIM * 129];              // [j][h] transposed, +1 pad
    __shared__ __align__(16) float h1s[2][HDIM * 8];
    const int tid = threadIdx.x;
    const int s = tid >> 7;
    const int h = tid & 127;

    for (int idx = tid; idx < HDIM * HDIM; idx += 256)
        w2sT[(idx & 127) * 129 + (idx >> 7)] = w2[idx];

    const int l0 = blockIdx.x * 16 + s * 8;
    const float myw1 = w1[h], myb1 = b1[h];
    #pragma unroll
    for (int ls = 0; ls < 8; ++ls) {
        float rel = -1.0f + (2.0f / 8191.0f) * (float)(l0 + ls);
        h1s[s][h * 8 + ls] = __sinf(30.0f * (rel * myw1 + myb1));
    }
    __syncthreads();

    const float bb = b2[h];
    float acc[8];
    #pragma unroll
    for (int ls = 0; ls < 8; ++ls) acc[ls] = bb;

    for (int j = 0; j < HDIM; ++j) {
        float wv = w2sT[j * 129 + h];
        const f32x4* hp = (const f32x4*)&h1s[s][j * 8];
        f32x4 p0 = hp[0], p1 = hp[1];
        acc[0] += wv * p0[0]; acc[1] += wv * p0[1];
        acc[2] += wv * p0[2]; acc[3] += wv * p0[3];
        acc[4] += wv * p1[0]; acc[5] += wv * p1[1];
        acc[6] += wv * p1[2]; acc[7] += wv * p1[3];
    }

    u32x4 ov;
    #pragma unroll
    for (int q = 0; q < 4; ++q) {
        unsigned lo = bf16_rne(__sinf(30.0f * acc[2 * q]));
        unsigned hi = bf16_rne(__sinf(30.0f * acc[2 * q + 1]));
        ov[q] = lo | (hi << 16);
    }
    const size_t c = (size_t)(l0 >> 6);
    const int k8 = (l0 >> 3) & 7;
    *(u32x4*)(h2T + (c * CUNITS + (size_t)k8 * 128 + h) * 8) = ov;
}

// ---------------- Kernel 2: gp[y] partial GEMM, x via LDS (channel-spread) ---
// Block 512 thr, BM=128 rows x BK=256 k. x loads are contiguous-per-row
// (4 rows x 512 B per wave-instr -> no L2 channel camping), cvt to bf16,
// ds_write with XOR swizzle (granule ^= row&7); A-frags read from LDS.
// B (h2T, 64 KB) staged once via global_load_lds. col128 = rowsum via shfl.
__global__ __launch_bounds__(512, 2) void k2_gemm(
        const float* __restrict__ x, const unsigned short* __restrict__ h2T,
        unsigned short* __restrict__ gp) {
    __shared__ unsigned short xl[2][BM * 128];     // 2 x 32768 B
    __shared__ unsigned short bs[4 * CUNITS * 8];  // 65536 B

    // bijective XCD swizzle: same-y blocks land on one XCD (B-plane L2 reuse)
    const int bid = blockIdx.x;                    // 0..1023
    const int swz = (bid & 7) * 128 + (bid >> 3);
    const int m0 = (swz & 31) * BM;
    const int y  = swz >> 5;

    const int t    = threadIdx.x;
    const int lane = t & 63;
    const int w    = t >> 6;
    const int r    = lane & 15;
    const int kg   = lane >> 4;
    const int rowl = t >> 4;        // staging row group 0..31
    const int cg   = t & 15;        // staging granule

    // B stage: 4096 16-B units, 8 per thread, linear
    {
        const unsigned short* src = h2T + (size_t)y * (4 * CUNITS) * 8;
        #pragma unroll
        for (int j = 0; j < 8; ++j) {
            const int U = j * 512 + t;
            __builtin_amdgcn_global_load_lds(
                (const unsigned int*)(src + (size_t)U * 8),
                (unsigned int*)&bs[U * 8], 16, 0, 0);
        }
    }

    const float* xb = x + (size_t)m0 * LPOS + (size_t)y * BK + cg * 8;

    f32x4 la[4][2];
    float rsum[4] = {0.f, 0.f, 0.f, 0.f};
    f32x4 acc[8];
    #pragma unroll
    for (int t8 = 0; t8 < 8; ++t8) { f32x4 z = {0.f,0.f,0.f,0.f}; acc[t8] = z; }

    auto load_half = [&](int hf) {
        #pragma unroll
        for (int s = 0; s < 4; ++s) {
            const float* p = xb + (size_t)(rowl + 32 * s) * LPOS + hf * 128;
            la[s][0] = *(const f32x4*)(p);
            la[s][1] = *(const f32x4*)(p + 4);
        }
    };
    auto cvt_write = [&](int hf) {
        #pragma unroll
        for (int s = 0; s < 4; ++s) {
            const int row = rowl + 32 * s;
            *(s16x8*)&xl[hf][row * 128 + ((cg ^ (row & 7)) * 8)] = cvt8(la[s][0], la[s][1]);
            float v = sum8(la[s][0], la[s][1]);
            v += __shfl_xor(v, 1); v += __shfl_xor(v, 2);
            v += __shfl_xor(v, 4); v += __shfl_xor(v, 8);
            rsum[s] += v;
        }
    };
    auto compute = [&](int hf) {
        const int row = w * 16 + r;
        #pragma unroll
        for (int cc = 0; cc < 2; ++cc) {
            s16x8 alo = *(const s16x8*)&xl[hf][row * 128 + (((cc * 8 + kg)     ^ (row & 7)) * 8)];
            s16x8 ahi = *(const s16x8*)&xl[hf][row * 128 + (((cc * 8 + 4 + kg) ^ (row & 7)) * 8)];
            const int cb = (hf * 2 + cc) * CUNITS;
            #pragma unroll
            for (int t8 = 0; t8 < 8; ++t8) {
                s16x8 blo = *(const s16x8*)&bs[(cb + kg * 128 + t8 * 16 + r) * 8];
                s16x8 bhi = *(const s16x8*)&bs[(cb + (kg + 4) * 128 + t8 * 16 + r) * 8];
                acc[t8] = __builtin_amdgcn_mfma_f32_16x16x32_bf16(alo, blo, acc[t8], 0, 0, 0);
                acc[t8] = __builtin_amdgcn_mfma_f32_16x16x32_bf16(ahi, bhi, acc[t8], 0, 0, 0);
            }
        }
    };

    load_half(0);
    cvt_write(0);
    __syncthreads();        // xl[0] + bs visible (drains vm+lgkm)
    load_half(1);           // issue BEFORE compute(0): HBM latency hides under MFMA
    compute(0);
    cvt_write(1);
    __syncthreads();
    compute(1);

    // epilogue: C/D layout col = t8*16 + r, row = w*16 + kg*4 + q
    unsigned short* gpy = gp + (size_t)y * GELEMS;
    #pragma unroll
    for (int t8 = 0; t8 < 8; ++t8) {
        const int col = t8 * 16 + r;
        #pragma unroll
        for (int q = 0; q < 4; ++q) {
            const int row = m0 + w * 16 + kg * 4 + q;
            gpy[(size_t)row * GROW + col] = bf16_rne(acc[t8][q]);
        }
    }
    if (cg == 0) {
        #pragma unroll
        for (int s = 0; s < 4; ++s)
            gpy[(size_t)(m0 + rowl + 32 * s) * GROW + 128] = bf16_rne(rsum[s]);
    }
}

// ---------------- reduce: g[f] = sum_y gp[y][f]  (bf16 -> f32) ---------------
__global__ __launch_bounds__(256) void reduce_g(
        const unsigned short* __restrict__ gp, float* __restrict__ g) {
    const int t = blockIdx.x * 256 + threadIdx.x;
    const unsigned int* p = (const unsigned int*)gp;
    float s0 = 0.f, s1 = 0.f, s2 = 0.f, s3 = 0.f;
    #pragma unroll 8
    for (int y = 0; y < KSPLIT; ++y) {
        u32x2 v = *(const u32x2*)(p + (size_t)y * (GELEMS / 2) + (size_t)t * 2);
        s0 += __builtin_bit_cast(float, v[0] << 16);
        s1 += __builtin_bit_cast(float, v[0] & 0xffff0000u);
        s2 += __builtin_bit_cast(float, v[1] << 16);
        s3 += __builtin_bit_cast(float, v[1] & 0xffff0000u);
    }
    f32x4 o = {s0, s1, s2, s3};
    *(f32x4*)(g + (size_t)t * 4) = o;
}

// ---------------- Kernel 3: out[b,o] = sum_{i,h} g[b,i,h]*w3e[o*64+i,h] ------
__global__ __launch_bounds__(256) void k3_contract(
        const float* __restrict__ g, const float* __restrict__ w3,
        const float* __restrict__ b3, const float* __restrict__ bias,
        float* __restrict__ out) {
    const int b = blockIdx.x >> 6;
    const int o = blockIdx.x & 63;
    const int t = threadIdx.x;
    const int i = t >> 2;
    const int q = t & 3;
    __shared__ float red[64];

    const float* gi = g + (size_t)(b * 64 + i) * GROW + q * 32;
    const float* wi = w3 + (size_t)(o * 64 + i) * HDIM + q * 32;
    float acc = 0.f;
    #pragma unroll
    for (int j = 0; j < 8; ++j) {
        f32x4 gv = *(const f32x4*)(gi + j * 4);
        f32x4 wv = *(const f32x4*)(wi + j * 4);
        acc += gv[0] * wv[0] + gv[1] * wv[1] + gv[2] * wv[2] + gv[3] * wv[3];
    }
    if (q == 0) acc += g[(size_t)(b * 64 + i) * GROW + 128] * b3[o * 64 + i];
    acc += __shfl_xor(acc, 1);
    acc += __shfl_xor(acc, 2);
    if (q == 0) red[i] = acc;
    __syncthreads();
    if (t < 64) {
        float v = red[t];
        v += __shfl_xor(v, 1);  v += __shfl_xor(v, 2);  v += __shfl_xor(v, 4);
        v += __shfl_xor(v, 8);  v += __shfl_xor(v, 16); v += __shfl_xor(v, 32);
        if (t == 0) out[blockIdx.x] = v + bias[o];
    }
}

extern "C" void kernel_launch(void* const* d_in, const int* in_sizes, int n_in,
                              void* d_out, int out_size, void* d_ws, size_t ws_size,
                              hipStream_t stream) {
    (void)in_sizes; (void)n_in; (void)out_size; (void)ws_size;
    const float* x    = (const float*)d_in[0];
    const float* w1   = (const float*)d_in[1];
    const float* b1   = (const float*)d_in[2];
    const float* w2   = (const float*)d_in[3];
    const float* b2   = (const float*)d_in[4];
    const float* w3   = (const float*)d_in[5];
    const float* b3   = (const float*)d_in[6];
    const float* bias = (const float*)d_in[7];
    float* out = (float*)d_out;

    unsigned short* h2T = (unsigned short*)d_ws;                       // 2.10 MB
    const size_t H2T_BYTES = (size_t)(LPOS / 64) * CUNITS * 16;
    unsigned short* gp = (unsigned short*)((char*)d_ws + H2T_BYTES);   // 34.6 MB
    const size_t GP_BYTES = (size_t)KSPLIT * GELEMS * 2;
    float* g = (float*)((char*)d_ws + H2T_BYTES + GP_BYTES);           // 2.16 MB

    k1_siren<<<LPOS / 16, 256, 0, stream>>>(w1, b1, w2, b2, h2T);
    k2_gemm<<<(M_TOT / BM) * KSPLIT, 512, 0, stream>>>(x, h2T, gp);
    reduce_g<<<GELEMS / 4 / 256, 256, 0, stream>>>(gp, g);
    k3_contract<<<64 * 64, 256, 0, stream>>>(g, w3, b3, bias, out);
}